// Round 16
// baseline (875.340 us; speedup 1.0000x reference)
//
#include <hip/hip_runtime.h>

// ConvNat: 2x NAT(31x31, 4 heads, dh=16) on 36x36x64 + dw-conv3x3 residual + linear.
// fp32. R15: 4 launches. Combine kernels fused into attention as a last-block
// epilogue (atomic ticket per tile, threadfence release/acquire): the 10th attn
// block of a tile re-reads the tile's 10 L2-hot partial records and runs the
// combine (+proj / +dwconv+linear). Counters zeroed in K1 each call.

namespace {

__device__ __forceinline__ int iclampi(int v, int lo, int hi) {
  return v < lo ? lo : (v > hi ? hi : v);
}

// K1/K3: qkv GEMM (planar out). Layer-1 variant also transposes weights and
// zeros the tile ticket counters.
// qkv blocks [0,1008): pg = bid%21 (64-pixel group), rg = bid/21 (4 rows of 192).
// x tile in LDS [64][65]; wave = one row x 64 pixels; coalesced planar writes.
// WITH_T blocks [1008,1056): transpose proj_w1/proj_w2/lin_w. Block 1056: zero
// 648 counters.
template <bool WITH_T>
__global__ __launch_bounds__(256) void qkv_fused(
    const float* __restrict__ xin, const float* __restrict__ w,
    const float* __restrict__ b, float* __restrict__ planes,
    const float* __restrict__ pw1, const float* __restrict__ pw2,
    const float* __restrict__ lw, float* __restrict__ wT,
    int* __restrict__ cnt) {
  const int bid = blockIdx.x;
  const int tid = threadIdx.x;
  if (WITH_T && bid >= 1008) {
    if (bid == 1056) {
      for (int i = tid; i < 648; i += 256) cnt[i] = 0;
      return;
    }
    const int t = bid - 1008;  // 0..47, 16 blocks per 64x64 matrix
    const int m = t >> 4;
    const int idx = (t & 15) * 256 + tid;
    const float* src = m == 0 ? pw1 : (m == 1 ? pw2 : lw);
    wT[m * 4096 + (idx & 63) * 64 + (idx >> 6)] = src[idx];
    return;
  }
  __shared__ float xs[64][65];
  __shared__ float ws4[4][64];
  const int pg = bid % 21, rg = bid / 21;
  const int wv = tid >> 6, lane = tid & 63;
  const int n0 = pg * 64;
  const int base = n0 * 64;
  const int maxf = 82944 - base;
  const float* xb = xin + base;
#pragma unroll
  for (int t4 = 0; t4 < 4; ++t4) {
    const int fi = (tid + t4 * 256) * 4;
    float4 v = make_float4(0.f, 0.f, 0.f, 0.f);
    if (fi < maxf) v = *(const float4*)(xb + fi);
    const int p = fi >> 6, c = fi & 63;
    xs[p][c] = v.x; xs[p][c + 1] = v.y; xs[p][c + 2] = v.z; xs[p][c + 3] = v.w;
  }
  ws4[tid >> 6][tid & 63] = w[rg * 256 + tid];
  __syncthreads();
  const int r = rg * 4 + wv;
  float acc = b[r];
#pragma unroll
  for (int cc = 0; cc < 64; ++cc) acc += xs[lane][cc] * ws4[wv][cc];
  const int n = n0 + lane;
  if (n < 1296) planes[r * 1296 + n] = acc;
}

// K2/K4: NAT partials (float4 full-row scan, as R14) + fused combine epilogue.
// grid = 3240: tile = bid/10, rem = bid%10, s = rem>>1 (5 row-splits of 7),
// prb = rem&1 (query row). Wave = head; lane = (rr = lane/9, cg = lane%9).
// Record per (bid, head): 36 floats [qq*17+d]=acc, [qq*17+16]=den.
// Epilogue (10th block of tile, atomic ticket): combine -> proj (FINAL: +dwconv
// residual + final linear) for the tile's 4 queries.
template <bool FINAL>
__global__ __launch_bounds__(256, 2) void nat_attn_fused(
    const float* __restrict__ planes, const float* __restrict__ rpb,
    float* __restrict__ part, int* __restrict__ cnt,
    const float* __restrict__ pwT, const float* __restrict__ pb,
    const float* __restrict__ x, const float* __restrict__ dww,
    const float* __restrict__ dwb, const float* __restrict__ linT,
    const float* __restrict__ lb, float* __restrict__ outp) {
  __shared__ float lpart[4][16][35];  // [head][group][2q*17] stride 35 (odd)
  __shared__ float qlds[4][2][16];    // [head][q][d], wave-private
  __shared__ float att[4][64];
  __shared__ float y_lds[4][64];
  __shared__ int ticket;

  const int tid = threadIdx.x;
  const int h = tid >> 6;
  const int lane = tid & 63;
  const int bid = blockIdx.x;
  const int tile = bid / 10;
  const int rem = bid - tile * 10;
  const int s = rem >> 1;
  const int prb = rem & 1;
  const int i0 = (tile / 18) * 2;
  const int j0 = (tile % 18) * 2;

  {
    const int iq = i0 + prb;
    const int riq = iclampi(iq - 15, 0, 5);
    const int jqa = j0, jqb = j0 + 1;
    const int cja = iclampi(jqa - 15, 0, 5);
    const int cjb = iclampi(jqb - 15, 0, 5);

    const float* Qp = planes + (size_t)(h * 16) * 1296;
    const float4* Kp4 = (const float4*)(planes + (size_t)(64 + h * 16) * 1296);
    const float4* Vp4 = (const float4*)(planes + (size_t)(128 + h * 16) * 1296);

    if (lane < 32) {
      const int qq = lane >> 4, dd = lane & 15;
      const int nq = iq * 36 + (qq ? jqb : jqa);
      qlds[h][qq][dd] = Qp[dd * 1296 + nq] * 0.25f;
    }

    const int rr = lane / 9;       // 0..7 (7 inactive)
    const int cg = lane - rr * 9;  // 0..8
    const int krr = s * 7 + rr;
    const int rA = riq + krr;
    const bool act = (krr <= 30) && (rr < 7);
    const int rL = rA > 35 ? 35 : rA;
    const int rc9 = rL * 9 + cg;
    const int br = iclampi(rA - iq + 30, 0, 60);
    const float* rpbh = rpb + h * 3721 + br * 61;

    // K pass
    float dta[4] = {0.f, 0.f, 0.f, 0.f};
    float dtb[4] = {0.f, 0.f, 0.f, 0.f};
#pragma unroll
    for (int d = 0; d < 16; ++d) {
      const float4 k4 = Kp4[d * 324 + rc9];
      const float qa = qlds[h][0][d], qb = qlds[h][1][d];
      dta[0] += qa * k4.x; dta[1] += qa * k4.y; dta[2] += qa * k4.z; dta[3] += qa * k4.w;
      dtb[0] += qb * k4.x; dtb[1] += qb * k4.y; dtb[2] += qb * k4.z; dtb[3] += qb * k4.w;
    }

    // softmax numerator weights
    float pa[4], pb_[4];
    float dena = 0.f, denb = 0.f;
#pragma unroll
    for (int j = 0; j < 4; ++j) {
      const int col = cg * 4 + j;
      const bool ina = act && (col >= cja) && (col <= cja + 30);
      const bool inb = act && (col >= cjb) && (col <= cjb + 30);
      const int bca = iclampi(col - jqa + 30, 0, 60);
      const int bcb = iclampi(col - jqb + 30, 0, 60);
      const float la = fminf(dta[j] + rpbh[bca], 25.f);  // overflow insurance
      const float lb_ = fminf(dtb[j] + rpbh[bcb], 25.f);
      pa[j] = ina ? __expf(la) : 0.f;
      pb_[j] = inb ? __expf(lb_) : 0.f;
      dena += pa[j];
      denb += pb_[j];
    }

    // V pass
    float acca[16], accb[16];
#pragma unroll
    for (int d = 0; d < 16; ++d) {
      const float4 v4 = Vp4[d * 324 + rc9];
      acca[d] = pa[0] * v4.x + pa[1] * v4.y + pa[2] * v4.z + pa[3] * v4.w;
      accb[d] = pb_[0] * v4.x + pb_[1] * v4.y + pb_[2] * v4.z + pb_[3] * v4.w;
    }

    // 2-step butterfly -> 16 groups of 4 lanes
#pragma unroll
    for (int d = 0; d < 16; ++d) {
      acca[d] += __shfl_xor(acca[d], 1);
      acca[d] += __shfl_xor(acca[d], 2);
      accb[d] += __shfl_xor(accb[d], 1);
      accb[d] += __shfl_xor(accb[d], 2);
    }
    dena += __shfl_xor(dena, 1);
    dena += __shfl_xor(dena, 2);
    denb += __shfl_xor(denb, 1);
    denb += __shfl_xor(denb, 2);

    if ((lane & 3) == 0) {
      const int row = lane >> 2;
#pragma unroll
      for (int d = 0; d < 16; ++d) {
        lpart[h][row][d] = acca[d];
        lpart[h][row][17 + d] = accb[d];
      }
      lpart[h][row][16] = dena;
      lpart[h][row][33] = denb;
    }
    // wave-private LDS slab: same wave writes+reads.

    float* wsout = part + ((size_t)bid * 4 + h) * 36;
    if (lane < 34) {
      float t0 = 0.f;
#pragma unroll
      for (int l = 0; l < 16; ++l) t0 += lpart[h][l][lane];
      wsout[lane] = t0;
    }
  }

  // --- ticket: last block of the tile runs the combine epilogue ---
  __threadfence();   // release this thread's record writes (device scope)
  __syncthreads();   // all waves' fences complete before tid0 proceeds
  if (tid == 0) ticket = atomicAdd(&cnt[tile], 1);
  __syncthreads();
  if (ticket != 9) return;
  __threadfence();   // acquire: other blocks' records now visible

  {
    const int q = tid >> 6;            // wave = query
    const int pre = q >> 1, qqe = q & 1;
    const int iq = i0 + pre, jq = j0 + qqe;
    const int n = iq * 36 + jq;

    const int hh = lane >> 4, dd = lane & 15;
    // record: part[tile*1440 + sp*288 + pre*144 + hh*36 + qqe*17 + {dd|16}]
    const float* pbase =
        part + (size_t)tile * 1440 + pre * 144 + hh * 36 + qqe * 17;
    float num = 0.f, den = 0.f;
#pragma unroll
    for (int sp = 0; sp < 5; ++sp) {
      num += pbase[sp * 288 + dd];
      den += pbase[sp * 288 + 16];
    }
    att[q][lane] = num / den;
    __syncthreads();

    float a = pb[lane];
#pragma unroll
    for (int cc = 0; cc < 64; ++cc) a += att[q][cc] * pwT[cc * 64 + lane];

    if (!FINAL) {
      outp[n * 64 + lane] = a;
    } else {
      float y = a + dwb[lane];
#pragma unroll
      for (int di = -1; di <= 1; ++di) {
#pragma unroll
        for (int dj = -1; dj <= 1; ++dj) {
          const int ii = iq + di, jj = jq + dj;
          if (ii >= 0 && ii < 36 && jj >= 0 && jj < 36)
            y += x[(ii * 36 + jj) * 64 + lane] *
                 dww[lane * 9 + (di + 1) * 3 + (dj + 1)];
        }
      }
      y_lds[q][lane] = y;
      __syncthreads();
      float o = lb[lane];
#pragma unroll
      for (int cc = 0; cc < 64; ++cc) o += y_lds[q][cc] * linT[cc * 64 + lane];
      outp[n * 64 + lane] = o;
    }
  }
}

}  // namespace

extern "C" void kernel_launch(void* const* d_in, const int* in_sizes, int n_in,
                              void* d_out, int out_size, void* d_ws, size_t ws_size,
                              hipStream_t stream) {
  const float* x       = (const float*)d_in[0];
  const float* qkv_w1  = (const float*)d_in[3];
  const float* qkv_b1  = (const float*)d_in[4];
  const float* rpb1    = (const float*)d_in[5];
  const float* proj_w1 = (const float*)d_in[6];
  const float* proj_b1 = (const float*)d_in[7];
  const float* qkv_w2  = (const float*)d_in[8];
  const float* qkv_b2  = (const float*)d_in[9];
  const float* rpb2    = (const float*)d_in[10];
  const float* proj_w2 = (const float*)d_in[11];
  const float* proj_b2 = (const float*)d_in[12];
  const float* dw_w    = (const float*)d_in[13];
  const float* dw_b    = (const float*)d_in[14];
  const float* lin_w   = (const float*)d_in[15];
  const float* lin_b   = (const float*)d_in[16];
  float* out = (float*)d_out;

  float* ws = (float*)d_ws;
  float* planes = ws;              // 192*1296  = 248832 floats
  float* natA   = ws + 248832;     // 1296*64   =  82944 floats
  float* partb  = natA + 82944;    // 3240*4*36 = 466560 floats
  float* wT     = partb + 466560;  // 3*4096    =  12288 floats
  float* pwT1 = wT;
  float* pwT2 = wT + 4096;
  float* linT = wT + 8192;
  int*   cnt  = (int*)(wT + 12288);  // 648 ints (cnt1: 324, cnt2: 324)

  // K1: qkv layer-1 + weight transposes + counter zeroing
  qkv_fused<true><<<1057, 256, 0, stream>>>(x, qkv_w1, qkv_b1, planes,
                                            proj_w1, proj_w2, lin_w, wT, cnt);
  // K2: attn layer-1 + fused combine (ticket) -> natA
  nat_attn_fused<false><<<3240, 256, 0, stream>>>(
      planes, rpb1, partb, cnt, pwT1, proj_b1, nullptr, nullptr, nullptr,
      nullptr, nullptr, natA);
  // K3: qkv layer-2
  qkv_fused<false><<<1008, 256, 0, stream>>>(natA, qkv_w2, qkv_b2, planes,
                                             nullptr, nullptr, nullptr, nullptr,
                                             nullptr);
  // K4: attn layer-2 + fused combine + dwconv residual + final linear -> out
  nat_attn_fused<true><<<3240, 256, 0, stream>>>(
      planes, rpb2, partb, cnt + 324, pwT2, proj_b2, x, dw_w, dw_b, linT,
      lin_b, out);
}

// Round 17
// 150.581 us; speedup vs baseline: 5.8131x; 5.8131x over previous
//
#include <hip/hip_runtime.h>

// ConvNat: 2x NAT(31x31, 4 heads, dh=16) on 36x36x64 + dw-conv3x3 residual + linear.
// fp32. R17: R14 structure (6 launches, measured best 149.5us). Attention now
// processes all 4 tile queries per block (grid 1620 = 324 tiles x 5 row-splits):
// K loaded once per 4 queries, V twice via two fully-unrolled V-passes with
// disjoint acc lifetimes (no dynamic indexing -> no scratch; avoids R13 spill).
// R16 lesson: per-block __threadfence ticket fusion = 10x regression. Never again.

namespace {

__device__ __forceinline__ int iclampi(int v, int lo, int hi) {
  return v < lo ? lo : (v > hi ? hi : v);
}

// Fused qkv GEMM (planar out) + (layer 1 only) proj/lin weight transposes.
// qkv blocks [0,1008): pg = bid%21 (64-pixel group), rg = bid/21 (4 rows of 192).
// x tile in LDS [64][65]; wave = one row x 64 pixels; coalesced planar writes.
// WITH_T blocks [1008,1056): transpose proj_w1/proj_w2/lin_w (64x64 each).
template <bool WITH_T>
__global__ __launch_bounds__(256) void qkv_fused(
    const float* __restrict__ xin, const float* __restrict__ w,
    const float* __restrict__ b, float* __restrict__ planes,
    const float* __restrict__ pw1, const float* __restrict__ pw2,
    const float* __restrict__ lw, float* __restrict__ wT) {
  const int bid = blockIdx.x;
  const int tid = threadIdx.x;
  if (WITH_T && bid >= 1008) {
    const int t = bid - 1008;  // 0..47, 16 blocks per 64x64 matrix
    const int m = t >> 4;
    const int idx = (t & 15) * 256 + tid;
    const float* src = m == 0 ? pw1 : (m == 1 ? pw2 : lw);
    wT[m * 4096 + (idx & 63) * 64 + (idx >> 6)] = src[idx];
    return;
  }
  __shared__ float xs[64][65];
  __shared__ float ws4[4][64];
  const int pg = bid % 21, rg = bid / 21;
  const int wv = tid >> 6, lane = tid & 63;
  const int n0 = pg * 64;
  const int base = n0 * 64;
  const int maxf = 82944 - base;
  const float* xb = xin + base;
#pragma unroll
  for (int t4 = 0; t4 < 4; ++t4) {
    const int fi = (tid + t4 * 256) * 4;
    float4 v = make_float4(0.f, 0.f, 0.f, 0.f);
    if (fi < maxf) v = *(const float4*)(xb + fi);
    const int p = fi >> 6, c = fi & 63;
    xs[p][c] = v.x; xs[p][c + 1] = v.y; xs[p][c + 2] = v.z; xs[p][c + 3] = v.w;
  }
  ws4[tid >> 6][tid & 63] = w[rg * 256 + tid];
  __syncthreads();
  const int r = rg * 4 + wv;
  float acc = b[r];
#pragma unroll
  for (int cc = 0; cc < 64; ++cc) acc += xs[lane][cc] * ws4[wv][cc];
  const int n = n0 + lane;
  if (n < 1296) planes[r * 1296 + n] = acc;
}

// NAT partials, float4 full-row scan, 4 queries (full 2x2 tile) per block.
// grid = 1620: tile = bid/5, s = bid%5 (row-split of 7). Wave = head.
// Lane = (rr = lane/9 in 0..6, cg = lane%9): key row r_lo + s*7 + rr,
// key cols 4*cg..4*cg+3 (full 0..35 scan; per-query window masks).
// Query qq = (pr<<1)|jj: pixel (i0+pr, j0+jj).
// K pass once (dt[4][4]); V passes pp=0,1 fully unrolled (acc lifetimes
// disjoint -> ~32 live acc regs, no dynamic indexing).
// Record per (bid, head): 72 floats [qq*17+d]=acc, [qq*17+16]=den.
__global__ __launch_bounds__(256, 2) void nat_attn_part(
    const float* __restrict__ planes, const float* __restrict__ rpb,
    float* __restrict__ part) {
  __shared__ float lpart[4][16][69];  // [head][group][4q*17] stride 69 (odd)
  __shared__ float qlds[4][4][16];    // [head][qq][d], wave-private

  const int tid = threadIdx.x;
  const int h = tid >> 6;
  const int lane = tid & 63;
  const int bid = blockIdx.x;
  const int tile = bid / 5;
  const int s = bid - tile * 5;
  const int i0 = (tile / 18) * 2;
  const int j0 = (tile % 18) * 2;

  const int riq0 = iclampi(i0 - 15, 0, 5);
  const int riq1 = iclampi(i0 - 14, 0, 5);
  const int cj0 = iclampi(j0 - 15, 0, 5);
  const int cj1 = iclampi(j0 - 14, 0, 5);
  const int nRr = (riq1 + 30) - riq0;  // 30 or 31

  const float* Qp = planes + (size_t)(h * 16) * 1296;
  const float4* Kp4 = (const float4*)(planes + (size_t)(64 + h * 16) * 1296);
  const float4* Vp4 = (const float4*)(planes + (size_t)(128 + h * 16) * 1296);

  // stage this wave's 4 queries (pre-scaled) into wave-private LDS
  {
    const int qq = lane >> 4, dd = lane & 15;
    const int nq = (i0 + (qq >> 1)) * 36 + j0 + (qq & 1);
    qlds[h][qq][dd] = Qp[dd * 1296 + nq] * 0.25f;
  }

  const int rr = lane / 9;       // 0..7 (7 inactive)
  const int cg = lane - rr * 9;  // 0..8
  const int krr = s * 7 + rr;
  const int rA = riq0 + krr;
  const bool act = (krr <= nRr) && (rr < 7);
  const int rL = rA > 35 ? 35 : rA;
  const int rc9 = rL * 9 + cg;
  const bool rowok0 = act && (rA >= riq0) && (rA <= riq0 + 30);
  const bool rowok1 = act && (rA >= riq1) && (rA <= riq1 + 30);
  const int br0 = iclampi(rA - i0 + 30, 0, 60);
  const int br1 = iclampi(rA - i0 + 29, 0, 60);
  const float* rpb0 = rpb + h * 3721 + br0 * 61;
  const float* rpb1 = rpb + h * 3721 + br1 * 61;

  // K pass: dt[qq][j] over 16 d (K loaded ONCE for all 4 queries)
  float dt0[4] = {0.f, 0.f, 0.f, 0.f};
  float dt1[4] = {0.f, 0.f, 0.f, 0.f};
  float dt2[4] = {0.f, 0.f, 0.f, 0.f};
  float dt3[4] = {0.f, 0.f, 0.f, 0.f};
#pragma unroll
  for (int d = 0; d < 16; ++d) {
    const float4 k4 = Kp4[d * 324 + rc9];
    const float q0 = qlds[h][0][d], q1 = qlds[h][1][d];
    const float q2 = qlds[h][2][d], q3 = qlds[h][3][d];
    dt0[0] += q0 * k4.x; dt0[1] += q0 * k4.y; dt0[2] += q0 * k4.z; dt0[3] += q0 * k4.w;
    dt1[0] += q1 * k4.x; dt1[1] += q1 * k4.y; dt1[2] += q1 * k4.z; dt1[3] += q1 * k4.w;
    dt2[0] += q2 * k4.x; dt2[1] += q2 * k4.y; dt2[2] += q2 * k4.z; dt2[3] += q2 * k4.w;
    dt3[0] += q3 * k4.x; dt3[1] += q3 * k4.y; dt3[2] += q3 * k4.z; dt3[3] += q3 * k4.w;
  }

  // softmax numerator weights (qq = pr*2 + jj)
  float p0[4], p1[4], p2[4], p3[4];
  float den0 = 0.f, den1 = 0.f, den2 = 0.f, den3 = 0.f;
#pragma unroll
  for (int j = 0; j < 4; ++j) {
    const int col = cg * 4 + j;
    const bool c0 = (col >= cj0) && (col <= cj0 + 30);
    const bool c1 = (col >= cj1) && (col <= cj1 + 30);
    const int bc0 = iclampi(col - j0 + 30, 0, 60);
    const int bc1 = iclampi(col - j0 + 29, 0, 60);
    const float b00 = rpb0[bc0], b01 = rpb0[bc1];
    const float b10 = rpb1[bc0], b11 = rpb1[bc1];
    p0[j] = (rowok0 && c0) ? __expf(fminf(dt0[j] + b00, 25.f)) : 0.f;
    p1[j] = (rowok0 && c1) ? __expf(fminf(dt1[j] + b01, 25.f)) : 0.f;
    p2[j] = (rowok1 && c0) ? __expf(fminf(dt2[j] + b10, 25.f)) : 0.f;
    p3[j] = (rowok1 && c1) ? __expf(fminf(dt3[j] + b11, 25.f)) : 0.f;
    den0 += p0[j]; den1 += p1[j]; den2 += p2[j]; den3 += p3[j];
  }

  // butterfly the denominators once
  den0 += __shfl_xor(den0, 1); den0 += __shfl_xor(den0, 2);
  den1 += __shfl_xor(den1, 1); den1 += __shfl_xor(den1, 2);
  den2 += __shfl_xor(den2, 1); den2 += __shfl_xor(den2, 2);
  den3 += __shfl_xor(den3, 1); den3 += __shfl_xor(den3, 2);
  if ((lane & 3) == 0) {
    const int row = lane >> 2;
    lpart[h][row][16] = den0;
    lpart[h][row][33] = den1;
    lpart[h][row][50] = den2;
    lpart[h][row][67] = den3;
  }

  // V pass 0 (queries 0,1) — acc lifetime ends at the lpart write
  {
    float acA[16], acB[16];
#pragma unroll
    for (int d = 0; d < 16; ++d) {
      const float4 v4 = Vp4[d * 324 + rc9];
      acA[d] = p0[0] * v4.x + p0[1] * v4.y + p0[2] * v4.z + p0[3] * v4.w;
      acB[d] = p1[0] * v4.x + p1[1] * v4.y + p1[2] * v4.z + p1[3] * v4.w;
    }
#pragma unroll
    for (int d = 0; d < 16; ++d) {
      acA[d] += __shfl_xor(acA[d], 1); acA[d] += __shfl_xor(acA[d], 2);
      acB[d] += __shfl_xor(acB[d], 1); acB[d] += __shfl_xor(acB[d], 2);
    }
    if ((lane & 3) == 0) {
      const int row = lane >> 2;
#pragma unroll
      for (int d = 0; d < 16; ++d) {
        lpart[h][row][d] = acA[d];
        lpart[h][row][17 + d] = acB[d];
      }
    }
  }
  // V pass 1 (queries 2,3)
  {
    float acA[16], acB[16];
#pragma unroll
    for (int d = 0; d < 16; ++d) {
      const float4 v4 = Vp4[d * 324 + rc9];
      acA[d] = p2[0] * v4.x + p2[1] * v4.y + p2[2] * v4.z + p2[3] * v4.w;
      acB[d] = p3[0] * v4.x + p3[1] * v4.y + p3[2] * v4.z + p3[3] * v4.w;
    }
#pragma unroll
    for (int d = 0; d < 16; ++d) {
      acA[d] += __shfl_xor(acA[d], 1); acA[d] += __shfl_xor(acA[d], 2);
      acB[d] += __shfl_xor(acB[d], 1); acB[d] += __shfl_xor(acB[d], 2);
    }
    if ((lane & 3) == 0) {
      const int row = lane >> 2;
#pragma unroll
      for (int d = 0; d < 16; ++d) {
        lpart[h][row][34 + d] = acA[d];
        lpart[h][row][51 + d] = acB[d];
      }
    }
  }
  // wave-private LDS slab: same wave writes+reads, no __syncthreads needed.

  float* wsout = part + ((size_t)bid * 4 + h) * 72;
  {
    float t0 = 0.f;
#pragma unroll
    for (int l = 0; l < 16; ++l) t0 += lpart[h][l][lane];
    wsout[lane] = t0;
    if (lane < 4) {
      float t1 = 0.f;
#pragma unroll
      for (int l = 0; l < 16; ++l) t1 += lpart[h][l][lane + 64];
      wsout[lane + 64] = t1;
    }
  }
}

// Combine partials -> normalize -> projection (transposed weights, coalesced).
// FINAL adds dwconv residual + final linear. grid = 324, block = 256 (wave=query).
// Record: part[((tile*5 + sp)*4 + hh)*72 + q*17 + {dd|16}], sp<5.
template <bool FINAL>
__global__ __launch_bounds__(256) void nat_combine(
    const float* __restrict__ part, const float* __restrict__ pwT,
    const float* __restrict__ pb, const float* __restrict__ x,
    const float* __restrict__ dww, const float* __restrict__ dwb,
    const float* __restrict__ linT, const float* __restrict__ lb,
    float* __restrict__ out) {
  __shared__ float att[4][64];
  __shared__ float y_lds[4][64];
  const int tid = threadIdx.x;
  const int q = tid >> 6, lane = tid & 63;
  const int tile = blockIdx.x;
  const int i0 = (tile / 18) * 2, j0 = (tile % 18) * 2;
  const int iq = i0 + (q >> 1), jq = j0 + (q & 1);
  const int n = iq * 36 + jq;

  const int hh = lane >> 4, dd = lane & 15;
  const float* pbase = part + ((size_t)tile * 5 * 4 + hh) * 72 + q * 17;
  float num = 0.f, den = 0.f;
#pragma unroll
  for (int sp = 0; sp < 5; ++sp) {
    num += pbase[sp * 288 + dd];
    den += pbase[sp * 288 + 16];
  }
  att[q][lane] = num / den;
  __syncthreads();

  float a = pb[lane];
#pragma unroll
  for (int cc = 0; cc < 64; ++cc) a += att[q][cc] * pwT[cc * 64 + lane];

  if (!FINAL) {
    out[n * 64 + lane] = a;
  } else {
    float y = a + dwb[lane];
#pragma unroll
    for (int di = -1; di <= 1; ++di) {
#pragma unroll
      for (int dj = -1; dj <= 1; ++dj) {
        const int ii = iq + di, jj = jq + dj;
        if (ii >= 0 && ii < 36 && jj >= 0 && jj < 36)
          y += x[(ii * 36 + jj) * 64 + lane] * dww[lane * 9 + (di + 1) * 3 + (dj + 1)];
      }
    }
    y_lds[q][lane] = y;
    __syncthreads();
    float o = lb[lane];
#pragma unroll
    for (int cc = 0; cc < 64; ++cc) o += y_lds[q][cc] * linT[cc * 64 + lane];
    out[n * 64 + lane] = o;
  }
}

}  // namespace

extern "C" void kernel_launch(void* const* d_in, const int* in_sizes, int n_in,
                              void* d_out, int out_size, void* d_ws, size_t ws_size,
                              hipStream_t stream) {
  const float* x       = (const float*)d_in[0];
  const float* qkv_w1  = (const float*)d_in[3];
  const float* qkv_b1  = (const float*)d_in[4];
  const float* rpb1    = (const float*)d_in[5];
  const float* proj_w1 = (const float*)d_in[6];
  const float* proj_b1 = (const float*)d_in[7];
  const float* qkv_w2  = (const float*)d_in[8];
  const float* qkv_b2  = (const float*)d_in[9];
  const float* rpb2    = (const float*)d_in[10];
  const float* proj_w2 = (const float*)d_in[11];
  const float* proj_b2 = (const float*)d_in[12];
  const float* dw_w    = (const float*)d_in[13];
  const float* dw_b    = (const float*)d_in[14];
  const float* lin_w   = (const float*)d_in[15];
  const float* lin_b   = (const float*)d_in[16];
  float* out = (float*)d_out;

  float* ws = (float*)d_ws;
  float* planes = ws;              // 192*1296  = 248832 floats
  float* natA   = ws + 248832;     // 1296*64   =  82944 floats
  float* partb  = natA + 82944;    // 1620*4*72 = 466560 floats
  float* wT     = partb + 466560;  // 3*4096    =  12288 floats
  float* pwT1 = wT;
  float* pwT2 = wT + 4096;
  float* linT = wT + 8192;

  // layer 1 (qkv + weight transposes fused into one launch)
  qkv_fused<true><<<1056, 256, 0, stream>>>(x, qkv_w1, qkv_b1, planes,
                                            proj_w1, proj_w2, lin_w, wT);
  nat_attn_part<<<1620, 256, 0, stream>>>(planes, rpb1, partb);
  nat_combine<false><<<324, 256, 0, stream>>>(partb, pwT1, proj_b1, nullptr,
                                              nullptr, nullptr, nullptr, nullptr,
                                              natA);
  // layer 2
  qkv_fused<false><<<1008, 256, 0, stream>>>(natA, qkv_w2, qkv_b2, planes,
                                             nullptr, nullptr, nullptr, nullptr);
  nat_attn_part<<<1620, 256, 0, stream>>>(planes, rpb2, partb);
  // layer-2 combine + dwconv residual + final linear
  nat_combine<true><<<324, 256, 0, stream>>>(partb, pwT2, proj_b2, x,
                                             dw_w, dw_b, linT, lin_b, out);
}